// Round 16
// baseline (923.803 us; speedup 1.0000x reference)
//
#include <hip/hip_runtime.h>
#include <stdint.h>

#define NCY 100000
#define NPR 50000
#define NT  150000
#define RREL 7
#define ETOT 2100000
#define EREL 300000
#define NSEG (RREL*NT)
#define NEG 0.2f

// two-pass sort geometry
#define NBUK 256
#define BWID 587
#define P1B  1024
#define CH1  2051
#define EPT  9
#define LSEG (RREL*BWID)
#define SPT  17

#define LSTR 128      // LDS row stride (u16); XOR granule swizzle

typedef __attribute__((ext_vector_type(8))) short short8;
typedef __attribute__((ext_vector_type(4))) float f32x4;
typedef unsigned short u16;

__device__ __forceinline__ float bf2f(u16 h){
  union{unsigned int u; float f;} v; v.u = ((unsigned int)h)<<16; return v.f;
}
__device__ __forceinline__ u16 f2bf(float f){
  union{unsigned int u; float f;} v; v.f=f;
  unsigned int u=v.u;
  return (u16)((u + 0x7fffu + ((u>>16)&1u))>>16);
}
__device__ __forceinline__ float lrelu(float x){ return x>0.f? x : NEG*x; }
__device__ __forceinline__ int lidx(int row, int col){
  return row*LSTR + ((((col>>4)^(row&7)))<<4) + (col&15);
}

#define MFMA(a,b,c) __builtin_amdgcn_mfma_f32_16x16x32_bf16(a,b,c,0,0,0)

// ============ two-pass counting sort (round-8 proven) ============
__global__ __launch_bounds__(256) void k_bin(const int* __restrict__ eidx,
    const float* __restrict__ ew,
    int* __restrict__ bsrc, int* __restrict__ bkey, float* __restrict__ bew,
    int* __restrict__ gcntT, int* __restrict__ poffT){
  __shared__ int cnt[NBUK];
  __shared__ int pb[NBUK];
  int blk = blockIdx.x, tid = threadIdx.x;
  int base = blk*CH1;
  int n = min(CH1, ETOT-base);
  cnt[tid]=0;
  __syncthreads();
  int esrc[EPT], ekey[EPT], erank[EPT], ebuk[EPT]; float eew[EPT];
  #pragma unroll
  for(int k=0;k<EPT;k++){
    int i = k*256 + tid;
    erank[k]=-1; esrc[k]=0; ekey[k]=0; ebuk[k]=0; eew[k]=0.f;
    if(i<n){
      int e = base+i;
      int2 sd = *(const int2*)(eidx+2*e);
      int r = e/EREL;
      int b = sd.y / BWID;
      esrc[k]=sd.x; ekey[k]=r*NT+sd.y; ebuk[k]=b;
      if(r==3) eew[k]=ew[e];                 // only rel 3 needs edge weights
      erank[k]=atomicAdd(&cnt[b],1);
    }
  }
  __syncthreads();
  int v = cnt[tid];
  pb[tid]=v; __syncthreads();
  for(int off=1; off<256; off<<=1){
    int a=(tid>=off)?pb[tid-off]:0; __syncthreads();
    pb[tid]+=a; __syncthreads();
  }
  int excl = pb[tid]-v;
  gcntT[blk*NBUK+tid]=v;
  poffT[blk*NBUK+tid]=excl;
  pb[tid]=excl; __syncthreads();
  #pragma unroll
  for(int k=0;k<EPT;k++){
    if(erank[k]>=0){
      int pos = base + pb[ebuk[k]] + erank[k];
      bsrc[pos]=esrc[k]; bkey[pos]=ekey[k];
      if(ekey[k]>=3*NT && ekey[k]<4*NT) bew[pos]=eew[k];
    }
  }
}

__global__ __launch_bounds__(256) void k_bsum(const int* __restrict__ gcntT,
                                              int* __restrict__ btot){
  __shared__ int lds[256];
  int b = blockIdx.x, t = threadIdx.x;
  int s=0;
  for(int blk=t; blk<P1B; blk+=256) s += gcntT[blk*NBUK+b];
  lds[t]=s; __syncthreads();
  for(int off=128; off>0; off>>=1){ if(t<off) lds[t]+=lds[t+off]; __syncthreads(); }
  if(t==0) btot[b]=lds[0];
}

__global__ __launch_bounds__(256) void k_bscan(const int* __restrict__ btot,
                                               int* __restrict__ bbase){
  __shared__ int lds[256];
  int t=threadIdx.x;
  int v=btot[t]; lds[t]=v; __syncthreads();
  for(int off=1; off<256; off<<=1){
    int a=(t>=off)?lds[t-off]:0; __syncthreads();
    lds[t]+=a; __syncthreads();
  }
  bbase[t]=lds[t]-v;
}

__global__ __launch_bounds__(256) void k_place(
    const int* __restrict__ bsrc, const int* __restrict__ bkey, const float* __restrict__ bew,
    const int* __restrict__ gcntT, const int* __restrict__ poffT, const int* __restrict__ bbase,
    int* __restrict__ starts_g, int* __restrict__ ends_g,
    int* __restrict__ ssrc, float* __restrict__ sew){
  __shared__ int scnt[LSEG];
  __shared__ int lrun[LSEG];
  __shared__ int gofs[P1B];
  __shared__ int gl[P1B];
  __shared__ int scan[256];
  int b = blockIdx.x, t = threadIdx.x;
  int lo = b*BWID;
  int gbase = bbase[b];
  for(int i=t;i<LSEG;i+=256) scnt[i]=0;
  for(int blk=t; blk<P1B; blk+=256){
    gl[blk]   = gcntT[blk*NBUK+b];
    gofs[blk] = poffT[blk*NBUK+b];
  }
  __syncthreads();
  for(int blk=t; blk<P1B; blk+=256){
    int o = blk*CH1 + gofs[blk], g = gl[blk];
    for(int i=0;i<g;i++){
      int key = bkey[o+i];
      int r = key/NT; int dst = key - r*NT;
      atomicAdd(&scnt[r*BWID + (dst-lo)], 1);
    }
  }
  __syncthreads();
  int ts=0;
  #pragma unroll
  for(int k=0;k<SPT;k++){ int idx=t*SPT+k; ts += (idx<LSEG)? scnt[idx]:0; }
  scan[t]=ts; __syncthreads();
  for(int off=1; off<256; off<<=1){
    int a=(t>=off)?scan[t-off]:0; __syncthreads();
    scan[t]+=a; __syncthreads();
  }
  int run = scan[t]-ts;
  #pragma unroll
  for(int k=0;k<SPT;k++){
    int idx=t*SPT+k;
    if(idx<LSEG){ lrun[idx]=run; run += scnt[idx]; }
  }
  __syncthreads();
  for(int idx=t; idx<LSEG; idx+=256){
    int r = idx/BWID; int ld = idx - r*BWID; int dst = lo+ld;
    if(dst<NT){
      int sgp = gbase + lrun[idx];
      starts_g[r*NT+dst] = sgp;
      ends_g[r*NT+dst]   = sgp + scnt[idx];
    }
  }
  __syncthreads();
  for(int idx=t; idx<LSEG; idx+=256) lrun[idx] += gbase;
  __syncthreads();
  for(int blk=t; blk<P1B; blk+=256){
    int o = blk*CH1 + gofs[blk], g = gl[blk];
    for(int i=0;i<g;i++){
      int key = bkey[o+i];
      int r = key/NT; int dst = key - r*NT;
      int pos = atomicAdd(&lrun[r*BWID+(dst-lo)], 1);
      ssrc[pos] = bsrc[o+i];
      if(r==3) sew[pos] = bew[o+i];
    }
  }
}

// ---------------- A_r = Wq_r Wk_r^T etc ----------------
__global__ __launch_bounds__(256) void k_prep(const float* __restrict__ Wq, const float* __restrict__ bq,
    const float* __restrict__ Wk, const float* __restrict__ bk,
    float* __restrict__ Ar, float* __restrict__ ur, float* __restrict__ wr,
    float* __restrict__ cr, int* __restrict__ bflag){
  int t = blockIdx.x*256 + threadIdx.x;
  if(t >= RREL*128*128) return;
  int r = t/(128*128); int ij = t - r*128*128; int i = ij>>7, j = ij&127;
  const float* wq = Wq + r*16384; const float* wk = Wk + r*16384;
  float s=0.f;
  for(int k=0;k<128;k++) s += wq[i*128+k]*wk[j*128+k];
  Ar[t] = s;
  if(i==0){
    float su=0.f, sw=0.f;
    for(int k=0;k<128;k++){ su += wq[j*128+k]*bk[r*128+k];
                            sw += wk[j*128+k]*bq[r*128+k]; }
    ur[r*128+j]=su; wr[r*128+j]=sw;
    if(j==0){
      float sc=0.f; int nz=0;
      for(int k=0;k<128;k++){ float a=bq[r*128+k], b2=bk[r*128+k];
        sc += a*b2; nz |= (a!=0.f)||(b2!=0.f); }
      cr[r]=sc; if(nz) atomicOr(bflag,1);
    }
  }
}

// ---------------- pack fp32 [K,128] into bf16 MFMA B-fragment layout ----------------
struct PackJob{ const float* src; u16* dst; int ksteps; };
struct PackJobs{ PackJob j[20]; };
__global__ __launch_bounds__(256) void k_pack(PackJobs jobs){
  PackJob J = jobs.j[blockIdx.y];
  int t = blockIdx.x*256 + threadIdx.x;
  int lane = t&63, ks=(t>>6)&7, nt=t>>9;
  if(ks >= J.ksteps) return;
  int col = nt*16 + (lane&15);
  int krow = ks*32 + (lane>>4)*8;
  u16* d = J.dst + ((nt*J.ksteps + ks)*64 + lane)*8;
  for(int j=0;j<8;j++) d[j] = f2bf(J.src[(krow+j)*128 + col]);
}

// ---------------- generic GEMM: EPI 0 emb->bf16, EPI 4 exp->bf16, EPI 3 final ----------------
struct GArgs {
  const void* A; const u16* B; int M; int rowoff;
  u16* outH; float* acc; float* den;
  const u16* emb16;
  const float* bv; const float* skip;
};

template<int EPI, int ASRC>
__global__ __launch_bounds__(256) void k_gemm(GArgs G)
{
  int wave = threadIdx.x>>6, lane = threadIdx.x&63;
  int M = G.M;
  int base = blockIdx.x*64 + wave*16;
  if(base >= M) return;
  int arow = base + (lane&15); if(arow >= M) arow = M-1;
  int kof = (lane>>4)*8;
  short8 a[4];
  if(ASRC==0){
    const u16* A = (const u16*)G.A;
    #pragma unroll
    for(int ks=0;ks<4;ks++) a[ks] = *(const short8*)(A + (size_t)arow*128 + ks*32 + kof);
  } else if(ASRC==3){
    const u16* A = (const u16*)G.A;
    float sc = 1.f/G.den[arow];
    #pragma unroll
    for(int ks=0;ks<4;ks++){
      short8 v = *(const short8*)(A + (size_t)arow*128 + ks*32 + kof);
      short8 s;
      #pragma unroll
      for(int j2=0;j2<8;j2++) s[j2]=f2bf(bf2f((u16)v[j2])*sc);
      a[ks]=s;
    }
  } else {
    const float* A = (const float*)G.A;
    #pragma unroll
    for(int ks=0;ks<4;ks++){
      const float* ap = A + (size_t)arow*128 + ks*32 + kof;
      f32x4 lo = *(const f32x4*)ap;
      f32x4 hi = *(const f32x4*)(ap+4);
      short8 s;
      #pragma unroll
      for(int j2=0;j2<4;j2++){ s[j2]=f2bf(lo[j2]); s[4+j2]=f2bf(hi[j2]); }
      a[ks]=s;
    }
  }
  f32x4 acc[8];
  #pragma unroll
  for(int nt=0;nt<8;nt++){
    f32x4 c = {0.f,0.f,0.f,0.f};
    #pragma unroll
    for(int ks=0;ks<4;ks++){
      short8 b = *(const short8*)(G.B + ((nt*4+ks)*64 + lane)*8);
      c = MFMA(a[ks], b, c);
    }
    acc[nt]=c;
  }
  int rbase = base + (lane>>4)*4;
  int cl = lane&15;
  if(EPI==0){
    #pragma unroll
    for(int nt=0;nt<8;nt++)
      for(int j=0;j<4;j++){
        int row=rbase+j;
        if(row<M){
          int col=nt*16+cl;
          G.outH[(size_t)(G.rowoff+row)*128+col] = f2bf(acc[nt][j]);
        }
      }
  } else if(EPI==4){
    #pragma unroll
    for(int nt=0;nt<8;nt++)
      for(int j=0;j<4;j++){
        int row=rbase+j;
        if(row<M){
          int col=nt*16+cl;
          G.outH[(size_t)row*128+col]=f2bf(__expf(acc[nt][j]));
        }
      }
  } else { // EPI==3
    float sg = 1.f/(1.f+__expf(-G.skip[0]));
    #pragma unroll
    for(int nt=0;nt<8;nt++)
      for(int j=0;j<4;j++){
        int row=rbase+j;
        if(row<M){
          int col=nt*16+cl;
          float x = bf2f(G.emb16[(size_t)row*128+col]);
          float g = 0.5f*x*(1.f+erff(x*0.70710678118f));
          G.acc[(size_t)row*128+col] = acc[nt][j] + G.bv[col] + sg*g;
        }
      }
  }
}

// ================= fused pair kernels =================
struct PArgs {
  const u16* emb16; const int* ssrc; const int* starts_g; const int* ends_g;
  const float* sew;
  const u16* ebR1; const u16* ebR2;
  const u16* pA1; const u16* pA2;
  const u16* pWr3;
  const u16* pB2a; const u16* pB2b; u16* ebW1; u16* ebW2;
  u16* acc16; float* den;
  const float* u1; const float* w1; const float* c1; const float* p1;
  const float* u2; const float* w2; const float* c2; const float* p2;
  const int* bflag;
  int r1, r2;
};

// single-relation gather (used by k_fp<1,0>): 2-pass, 8 thr/node, 2-edge unroll (round-13 proven)
__device__ __forceinline__ void gatherAtt(u16* buf, const u16* __restrict__ ebt,
    const u16* __restrict__ emb16, const int* __restrict__ ssrc,
    const int* __restrict__ sg, const int* __restrict__ eg,
    int rel, int base64, int tid){
  #pragma unroll
  for(int p2=0;p2<2;p2++){
    int ln = (tid>>3) + p2*32;
    int gn = base64 + ln;
    int cb = (tid&7)*16;
    float num[16]={0,0,0,0,0,0,0,0,0,0,0,0,0,0,0,0};
    float den[16]={0,0,0,0,0,0,0,0,0,0,0,0,0,0,0,0};
    if(gn<NT){
      int s=sg[rel*NT+gn], e=eg[rel*NT+gn];
      int pos=s;
      for(; pos+1<e; pos+=2){
        int s0=ssrc[pos], s1=ssrc[pos+1];
        const u16* eb0=ebt+(size_t)s0*128+cb;   const u16* xm0=emb16+(size_t)s0*128+cb;
        const u16* eb1=ebt+(size_t)s1*128+cb;   const u16* xm1=emb16+(size_t)s1*128+cb;
        short8 ea0=*(const short8*)eb0, ea1=*(const short8*)(eb0+8);
        short8 xa0=*(const short8*)xm0, xa1=*(const short8*)(xm0+8);
        short8 eb0v=*(const short8*)eb1, eb1v=*(const short8*)(eb1+8);
        short8 xb0=*(const short8*)xm1, xb1=*(const short8*)(xm1+8);
        #pragma unroll
        for(int j=0;j<8;j++){
          float e00=bf2f((u16)ea0[j]), e01=bf2f((u16)ea1[j]);
          float e10=bf2f((u16)eb0v[j]), e11=bf2f((u16)eb1v[j]);
          num[j]   += bf2f((u16)xa0[j])*e00 + bf2f((u16)xb0[j])*e10;
          den[j]   += e00 + e10;
          num[8+j] += bf2f((u16)xa1[j])*e01 + bf2f((u16)xb1[j])*e11;
          den[8+j] += e01 + e11;
        }
      }
      if(pos<e){
        int s0=ssrc[pos];
        const u16* eb0=ebt+(size_t)s0*128+cb;  const u16* xm0=emb16+(size_t)s0*128+cb;
        short8 ea0=*(const short8*)eb0, ea1=*(const short8*)(eb0+8);
        short8 xa0=*(const short8*)xm0, xa1=*(const short8*)(xm0+8);
        #pragma unroll
        for(int j=0;j<8;j++){
          float e00=bf2f((u16)ea0[j]), e01=bf2f((u16)ea1[j]);
          num[j]   += bf2f((u16)xa0[j])*e00; den[j]   += e00;
          num[8+j] += bf2f((u16)xa1[j])*e01; den[8+j] += e01;
        }
      }
    }
    short8 v0, v1;
    #pragma unroll
    for(int j=0;j<8;j++){
      v0[j] = (short)f2bf(lrelu(num[j]/(den[j]+1e-16f)));
      v1[j] = (short)f2bf(lrelu(num[8+j]/(den[8+j]+1e-16f)));
    }
    int g1 = (tid&7) ^ (ln&7);
    u16* wp = buf + ln*LSTR + g1*16;
    *(short8*)wp = v0;
    *(short8*)(wp+8) = v1;
  }
}

// DUAL-relation gather: both segments walked in ONE loop, loads issued for both
// relations before either accumulate -> 2 independent latency chains in flight.
// Per-relation accumulation order: sequential single-edge (numerics within bf16 rounding).
__device__ __forceinline__ void gatherAtt2(u16* buf1, u16* buf2,
    const u16* __restrict__ ebt1, const u16* __restrict__ ebt2,
    const u16* __restrict__ emb16, const int* __restrict__ ssrc,
    const int* __restrict__ sg, const int* __restrict__ eg,
    int r1, int r2, int base64, int tid){
  #pragma unroll
  for(int p2=0;p2<2;p2++){
    int ln = (tid>>3) + p2*32;
    int gn = base64 + ln;
    int cb = (tid&7)*16;
    float numA[16]={0,0,0,0,0,0,0,0,0,0,0,0,0,0,0,0};
    float denA[16]={0,0,0,0,0,0,0,0,0,0,0,0,0,0,0,0};
    float numB[16]={0,0,0,0,0,0,0,0,0,0,0,0,0,0,0,0};
    float denB[16]={0,0,0,0,0,0,0,0,0,0,0,0,0,0,0,0};
    if(gn<NT){
      int sA=sg[r1*NT+gn], lA=eg[r1*NT+gn]-sA;
      int sB=sg[r2*NT+gn], lB=eg[r2*NT+gn]-sB;
      int mx = lA>lB? lA:lB;
      for(int i=0;i<mx;i++){
        bool hA=i<lA, hB=i<lB;
        short8 ea0,ea1,xa0,xa1, eb0,eb1,xb0,xb1;
        if(hA){
          int s0=ssrc[sA+i];
          const u16* ep=ebt1+(size_t)s0*128+cb; const u16* xp=emb16+(size_t)s0*128+cb;
          ea0=*(const short8*)ep; ea1=*(const short8*)(ep+8);
          xa0=*(const short8*)xp; xa1=*(const short8*)(xp+8);
        }
        if(hB){
          int s0=ssrc[sB+i];
          const u16* ep=ebt2+(size_t)s0*128+cb; const u16* xp=emb16+(size_t)s0*128+cb;
          eb0=*(const short8*)ep; eb1=*(const short8*)(ep+8);
          xb0=*(const short8*)xp; xb1=*(const short8*)(xp+8);
        }
        if(hA){
          #pragma unroll
          for(int j=0;j<8;j++){
            float e0=bf2f((u16)ea0[j]), e1=bf2f((u16)ea1[j]);
            numA[j]   += bf2f((u16)xa0[j])*e0; denA[j]   += e0;
            numA[8+j] += bf2f((u16)xa1[j])*e1; denA[8+j] += e1;
          }
        }
        if(hB){
          #pragma unroll
          for(int j=0;j<8;j++){
            float e0=bf2f((u16)eb0[j]), e1=bf2f((u16)eb1[j]);
            numB[j]   += bf2f((u16)xb0[j])*e0; denB[j]   += e0;
            numB[8+j] += bf2f((u16)xb1[j])*e1; denB[8+j] += e1;
          }
        }
      }
    }
    int g1 = (tid&7) ^ (ln&7);
    short8 v0, v1;
    #pragma unroll
    for(int j=0;j<8;j++){
      v0[j] = (short)f2bf(lrelu(numA[j]/(denA[j]+1e-16f)));
      v1[j] = (short)f2bf(lrelu(numA[8+j]/(denA[8+j]+1e-16f)));
    }
    { u16* wp = buf1 + ln*LSTR + g1*16; *(short8*)wp = v0; *(short8*)(wp+8) = v1; }
    #pragma unroll
    for(int j=0;j<8;j++){
      v0[j] = (short)f2bf(lrelu(numB[j]/(denB[j]+1e-16f)));
      v1[j] = (short)f2bf(lrelu(numB[8+j]/(denB[8+j]+1e-16f)));
    }
    { u16* wp = buf2 + ln*LSTR + g1*16; *(short8*)wp = v0; *(short8*)(wp+8) = v1; }
  }
}

// DUAL gather for k_fp0: rel-3 weighted mean (buf1, no lrelu) + att rel r2 (buf2)
__device__ __forceinline__ void gatherR3A(u16* buf1, u16* buf2,
    const float* __restrict__ sew, const u16* __restrict__ ebt2,
    const u16* __restrict__ emb16, const int* __restrict__ ssrc,
    const int* __restrict__ sg, const int* __restrict__ eg,
    int r2, int base64, int tid){
  #pragma unroll
  for(int p2=0;p2<2;p2++){
    int ln = (tid>>3) + p2*32;
    int gn = base64 + ln;
    int cb = (tid&7)*16;
    float numR[16]={0,0,0,0,0,0,0,0,0,0,0,0,0,0,0,0};
    float dnR=0.f;
    float numB[16]={0,0,0,0,0,0,0,0,0,0,0,0,0,0,0,0};
    float denB[16]={0,0,0,0,0,0,0,0,0,0,0,0,0,0,0,0};
    if(gn<NT){
      int sA=sg[3*NT+gn], lA=eg[3*NT+gn]-sA;
      int sB=sg[r2*NT+gn], lB=eg[r2*NT+gn]-sB;
      int mx = lA>lB? lA:lB;
      for(int i=0;i<mx;i++){
        bool hA=i<lA, hB=i<lB;
        short8 xa0,xa1, eb0,eb1,xb0,xb1;
        float w0=0.f;
        if(hA){
          int s0=ssrc[sA+i];
          w0=__expf(sew[sA+i]);
          const u16* xp=emb16+(size_t)s0*128+cb;
          xa0=*(const short8*)xp; xa1=*(const short8*)(xp+8);
        }
        if(hB){
          int s0=ssrc[sB+i];
          const u16* ep=ebt2+(size_t)s0*128+cb; const u16* xp=emb16+(size_t)s0*128+cb;
          eb0=*(const short8*)ep; eb1=*(const short8*)(ep+8);
          xb0=*(const short8*)xp; xb1=*(const short8*)(xp+8);
        }
        if(hA){
          dnR += w0;
          #pragma unroll
          for(int j=0;j<8;j++){
            numR[j]   += w0*bf2f((u16)xa0[j]);
            numR[8+j] += w0*bf2f((u16)xa1[j]);
          }
        }
        if(hB){
          #pragma unroll
          for(int j=0;j<8;j++){
            float e0=bf2f((u16)eb0[j]), e1=bf2f((u16)eb1[j]);
            numB[j]   += bf2f((u16)xb0[j])*e0; denB[j]   += e0;
            numB[8+j] += bf2f((u16)xb1[j])*e1; denB[8+j] += e1;
          }
        }
      }
    }
    int g1 = (tid&7) ^ (ln&7);
    float inv = 1.f/(dnR+1e-16f);
    short8 v0, v1;
    #pragma unroll
    for(int j=0;j<8;j++){
      v0[j] = (short)f2bf(numR[j]*inv);
      v1[j] = (short)f2bf(numR[8+j]*inv);
    }
    { u16* wp = buf1 + ln*LSTR + g1*16; *(short8*)wp = v0; *(short8*)(wp+8) = v1; }
    #pragma unroll
    for(int j=0;j<8;j++){
      v0[j] = (short)f2bf(lrelu(numB[j]/(denB[j]+1e-16f)));
      v1[j] = (short)f2bf(lrelu(numB[8+j]/(denB[8+j]+1e-16f)));
    }
    { u16* wp = buf2 + ln*LSTR + g1*16; *(short8*)wp = v0; *(short8*)(wp+8) = v1; }
  }
}

// generic fused pair kernel. NR = #relations, NEB = #ebot emits. (RMW acc)
template<int NR, int NEB>
__global__ __launch_bounds__(256) void k_fp(PArgs P)
{
  __shared__ u16 ldsA[(NR==2 ? 2 : 1)*64*LSTR];
  u16* lds1 = ldsA;
  u16* lds2 = ldsA + (NR==2 ? 64*LSTR : 0);
  int tid = threadIdx.x;
  int base64 = blockIdx.x*64;
  if(NR==2){
    gatherAtt2(lds1, lds2, P.ebR1, P.ebR2, P.emb16, P.ssrc, P.starts_g, P.ends_g,
               P.r1, P.r2, base64, tid);
  } else {
    gatherAtt(lds1, P.ebR1, P.emb16, P.ssrc, P.starts_g, P.ends_g, P.r1, base64, tid);
  }
  __syncthreads();
  int wave=tid>>6, lane=tid&63;
  int base = base64 + wave*16;
  if(base >= NT) return;
  int arow = base + (lane&15); if(arow >= NT) arow = NT-1;
  int kof = (lane>>4)*8;
  short8 a[4];
  #pragma unroll
  for(int ks=0;ks<4;ks++) a[ks] = *(const short8*)(P.emb16 + (size_t)arow*128 + ks*32 + kof);
  int rbase = base + (lane>>4)*4;
  int lrb   = wave*16 + (lane>>4)*4;
  int cl = lane&15;
  int bias = *P.bflag;
  float e1v[4], e2v[4];
  // --- score r1 ---
  {
    f32x4 accS[8];
    #pragma unroll
    for(int nt=0;nt<8;nt++){
      f32x4 c = {0.f,0.f,0.f,0.f};
      #pragma unroll
      for(int ks=0;ks<4;ks++){
        short8 b = *(const short8*)(P.pA1 + ((nt*4+ks)*64 + lane)*8);
        c = MFMA(a[ks], b, c);
      }
      accS[nt]=c;
    }
    float prival = P.p1[0]*0.08838834764831845f;
    #pragma unroll
    for(int j=0;j<4;j++){
      int row=rbase+j; bool ok=row<NT;
      float p=0.f;
      if(ok){
        #pragma unroll
        for(int nt=0;nt<8;nt++){
          int col=nt*16+cl;
          float rv = bf2f(lds1[lidx(lrb+j,col)]);
          p += accS[nt][j]*rv;
          if(bias) p += bf2f(P.emb16[(size_t)row*128+col])*P.u1[col] + rv*P.w1[col];
        }
      }
      p += __shfl_xor(p,1,16); p += __shfl_xor(p,2,16);
      p += __shfl_xor(p,4,16); p += __shfl_xor(p,8,16);
      e1v[j] = __expf((p + P.c1[0])*prival);
    }
  }
  // --- score r2 ---
  if(NR==2){
    f32x4 accS[8];
    #pragma unroll
    for(int nt=0;nt<8;nt++){
      f32x4 c = {0.f,0.f,0.f,0.f};
      #pragma unroll
      for(int ks=0;ks<4;ks++){
        short8 b = *(const short8*)(P.pA2 + ((nt*4+ks)*64 + lane)*8);
        c = MFMA(a[ks], b, c);
      }
      accS[nt]=c;
    }
    float prival = P.p2[0]*0.08838834764831845f;
    #pragma unroll
    for(int j=0;j<4;j++){
      int row=rbase+j; bool ok=row<NT;
      float p=0.f;
      if(ok){
        #pragma unroll
        for(int nt=0;nt<8;nt++){
          int col=nt*16+cl;
          float rv = bf2f(lds2[lidx(lrb+j,col)]);
          p += accS[nt][j]*rv;
          if(bias) p += bf2f(P.emb16[(size_t)row*128+col])*P.u2[col] + rv*P.w2[col];
        }
      }
      p += __shfl_xor(p,1,16); p += __shfl_xor(p,2,16);
      p += __shfl_xor(p,4,16); p += __shfl_xor(p,8,16);
      e2v[j] = __expf((p + P.c2[0])*prival);
    }
  }
  // --- single RMW accumulate ---
  #pragma unroll
  for(int j=0;j<4;j++){
    int row=rbase+j;
    if(row<NT){
      float ee1=e1v[j];
      float ee2=(NR==2)? e2v[j] : 0.f;
      #pragma unroll
      for(int nt=0;nt<8;nt++){
        int col=nt*16+cl;
        size_t o=(size_t)row*128+col;
        float add = ee1*bf2f(lds1[lidx(lrb+j,col)]);
        if(NR==2) add += ee2*bf2f(lds2[lidx(lrb+j,col)]);
        P.acc16[o] = f2bf(bf2f(P.acc16[o]) + add);
      }
      if(cl==0) P.den[row] += ee1 + ee2;
    }
  }
  // --- emit next ebot tables ---
  if(NEB>=1){
    #pragma unroll
    for(int nt=0;nt<8;nt++){
      f32x4 c = {0.f,0.f,0.f,0.f};
      #pragma unroll
      for(int ks=0;ks<4;ks++){
        short8 b = *(const short8*)(P.pB2a + ((nt*4+ks)*64 + lane)*8);
        c = MFMA(a[ks], b, c);
      }
      #pragma unroll
      for(int j=0;j<4;j++){
        int row=rbase+j;
        if(row<NT) P.ebW1[(size_t)row*128 + nt*16+cl] = f2bf(__expf(c[j]));
      }
    }
  }
  if(NEB>=2){
    #pragma unroll
    for(int nt=0;nt<8;nt++){
      f32x4 c = {0.f,0.f,0.f,0.f};
      #pragma unroll
      for(int ks=0;ks<4;ks++){
        short8 b = *(const short8*)(P.pB2b + ((nt*4+ks)*64 + lane)*8);
        c = MFMA(a[ks], b, c);
      }
      #pragma unroll
      for(int j=0;j<4;j++){
        int row=rbase+j;
        if(row<NT) P.ebW2[(size_t)row*128 + nt*16+cl] = f2bf(__expf(c[j]));
      }
    }
  }
}

// fused pair (rel3, rel0): FIRST accumulator -> STORE acc/den (no RMW, no memset needed)
__global__ __launch_bounds__(256) void k_fp0(PArgs P)
{
  __shared__ u16 lds1[64*LSTR];   // t3 (A-layout consumption)
  __shared__ u16 lds2[64*LSTR];   // rs0
  int tid = threadIdx.x;
  int base64 = blockIdx.x*64;
  gatherR3A(lds1, lds2, P.sew, P.ebR2, P.emb16, P.ssrc, P.starts_g, P.ends_g,
            P.r2, base64, tid);
  __syncthreads();
  int wave=tid>>6, lane=tid&63;
  int base = base64 + wave*16;
  if(base >= NT) return;
  int arow = base + (lane&15); if(arow >= NT) arow = NT-1;
  int hi = lane>>4;
  int kof = hi*8;
  int lar = wave*16 + (lane&15);
  short8 a[4];
  #pragma unroll
  for(int ks=0;ks<4;ks++) a[ks] = *(const short8*)(P.emb16 + (size_t)arow*128 + ks*32 + kof);
  // rs3 = lrelu(t3 @ Wrel3) from swizzled lds1
  f32x4 rs3[8];
  {
    short8 ta[4];
    #pragma unroll
    for(int ks=0;ks<4;ks++){
      int g = ((ks<<1)+(hi>>1)) ^ (lar&7);
      ta[ks] = *(const short8*)(lds1 + lar*LSTR + g*16 + ((hi&1)<<3));
    }
    #pragma unroll
    for(int nt=0;nt<8;nt++){
      f32x4 c = {0.f,0.f,0.f,0.f};
      #pragma unroll
      for(int ks=0;ks<4;ks++){
        short8 b = *(const short8*)(P.pWr3 + ((nt*4+ks)*64 + lane)*8);
        c = MFMA(ta[ks], b, c);
      }
      #pragma unroll
      for(int j=0;j<4;j++) c[j] = lrelu(c[j]);
      rs3[nt]=c;
    }
  }
  int rbase = base + (lane>>4)*4;
  int lrb   = wave*16 + (lane>>4)*4;
  int cl = lane&15;
  int bias = *P.bflag;
  float e1v[4], e2v[4];
  // --- score rel3 (rs from registers) ---
  {
    f32x4 accS[8];
    #pragma unroll
    for(int nt=0;nt<8;nt++){
      f32x4 c = {0.f,0.f,0.f,0.f};
      #pragma unroll
      for(int ks=0;ks<4;ks++){
        short8 b = *(const short8*)(P.pA1 + ((nt*4+ks)*64 + lane)*8);
        c = MFMA(a[ks], b, c);
      }
      accS[nt]=c;
    }
    float prival = P.p1[0]*0.08838834764831845f;
    #pragma unroll
    for(int j=0;j<4;j++){
      int row=rbase+j; bool ok=row<NT;
      float p=0.f;
      if(ok){
        #pragma unroll
        for(int nt=0;nt<8;nt++){
          int col=nt*16+cl;
          float rv = rs3[nt][j];
          p += accS[nt][j]*rv;
          if(bias) p += bf2f(P.emb16[(size_t)row*128+col])*P.u1[col] + rv*P.w1[col];
        }
      }
      p += __shfl_xor(p,1,16); p += __shfl_xor(p,2,16);
      p += __shfl_xor(p,4,16); p += __shfl_xor(p,8,16);
      e1v[j] = __expf((p + P.c1[0])*prival);
    }
  }
  // --- score rel0 (rs from LDS) ---
  {
    f32x4 accS[8];
    #pragma unroll
    for(int nt=0;nt<8;nt++){
      f32x4 c = {0.f,0.f,0.f,0.f};
      #pragma unroll
      for(int ks=0;ks<4;ks++){
        short8 b = *(const short8*)(P.pA2 + ((nt*4+ks)*64 + lane)*8);
        c = MFMA(a[ks], b, c);
      }
      accS[nt]=c;
    }
    float prival = P.p2[0]*0.08838834764831845f;
    #pragma unroll
    for(int j=0;j<4;j++){
      int row=rbase+j; bool ok=row<NT;
      float p=0.f;
      if(ok){
        #pragma unroll
        for(int nt=0;nt<8;nt++){
          int col=nt*16+cl;
          float rv = bf2f(lds2[lidx(lrb+j,col)]);
          p += accS[nt][j]*rv;
          if(bias) p += bf2f(P.emb16[(size_t)row*128+col])*P.u2[col] + rv*P.w2[col];
        }
      }
      p += __shfl_xor(p,1,16); p += __shfl_xor(p,2,16);
      p += __shfl_xor(p,4,16); p += __shfl_xor(p,8,16);
      e2v[j] = __expf((p + P.c2[0])*prival);
    }
  }
  // --- STORE (first accumulator; f2bf(x) == f2bf(0+x), bit-identical to memset+RMW) ---
  #pragma unroll
  for(int j=0;j<4;j++){
    int row=rbase+j;
    if(row<NT){
      float ee1=e1v[j], ee2=e2v[j];
      #pragma unroll
      for(int nt=0;nt<8;nt++){
        int col=nt*16+cl;
        size_t o=(size_t)row*128+col;
        float add = ee1*bf2f(f2bf(rs3[nt][j])) + ee2*bf2f(lds2[lidx(lrb+j,col)]);
        P.acc16[o] = f2bf(add);
      }
      if(cl==0) P.den[row] = ee1 + ee2;
    }
  }
  // --- emit ebot for rel1, rel2 ---
  #pragma unroll
  for(int nt=0;nt<8;nt++){
    f32x4 c = {0.f,0.f,0.f,0.f};
    #pragma unroll
    for(int ks=0;ks<4;ks++){
      short8 b = *(const short8*)(P.pB2a + ((nt*4+ks)*64 + lane)*8);
      c = MFMA(a[ks], b, c);
    }
    #pragma unroll
    for(int j=0;j<4;j++){
      int row=rbase+j;
      if(row<NT) P.ebW1[(size_t)row*128 + nt*16+cl] = f2bf(__expf(c[j]));
    }
  }
  #pragma unroll
  for(int nt=0;nt<8;nt++){
    f32x4 c = {0.f,0.f,0.f,0.f};
    #pragma unroll
    for(int ks=0;ks<4;ks++){
      short8 b = *(const short8*)(P.pB2b + ((nt*4+ks)*64 + lane)*8);
      c = MFMA(a[ks], b, c);
    }
    #pragma unroll
    for(int j=0;j<4;j++){
      int row=rbase+j;
      if(row<NT) P.ebW2[(size_t)row*128 + nt*16+cl] = f2bf(__expf(c[j]));
    }
  }
}

extern "C" void kernel_launch(void* const* d_in, const int* in_sizes, int n_in,
                              void* d_out, int out_size, void* d_ws, size_t ws_size,
                              hipStream_t stream){
  const float* company = (const float*)d_in[0];
  const float* person  = (const float*)d_in[1];
  const float* eweight = (const float*)d_in[2];
  const float* W_com   = (const float*)d_in[3];
  const float* W_per   = (const float*)d_in[4];
  const float* Wq      = (const float*)d_in[5];
  const float* bq      = (const float*)d_in[6];
  const float* Wk      = (const float*)d_in[7];
  const float* bk      = (const float*)d_in[8];
  const float* Wv      = (const float*)d_in[9];
  const float* bvv     = (const float*)d_in[10];
  const float* pri     = (const float*)d_in[11];
  const float* Wpair   = (const float*)d_in[12];
  const float* Wrel3   = (const float*)d_in[13];
  const float* skip    = (const float*)d_in[14];
  const int*   eidx    = (const int*)d_in[15];
  float* out = (float*)d_out;

  // workspace (~181 MB, known-good level)
  char* w = (char*)d_ws;
  auto alloc = [&](size_t sz)->void*{ void* p=(void*)w; w += (sz+255)&~(size_t)255; return p; };
  u16*   emb16 = (u16*)alloc((size_t)NT*128*2);
  u16*   ebA   = (u16*)alloc((size_t)NT*128*2);        // aliases sort bsrc/bkey/bew
  u16*   ebB   = (u16*)alloc((size_t)NT*128*2);
  u16*   acc16 = (u16*)alloc((size_t)NT*128*2);        // aliases gcntT/poffT/btot/bbase
  float* den   = (float*)alloc((size_t)NT*4);
  int*   starts_g = (int*)alloc((size_t)NSEG*4);
  int*   ends_g   = (int*)alloc((size_t)NSEG*4);
  int*   ssrc  = (int*)alloc((size_t)ETOT*4);
  float* sew   = (float*)alloc((size_t)ETOT*4);
  float* Ar    = (float*)alloc((size_t)RREL*16384*4);
  float* ur    = (float*)alloc(RREL*128*4);
  float* wr    = (float*)alloc(RREL*128*4);
  float* cr    = (float*)alloc(RREL*4);
  int*   bflag = (int*)alloc(256);
  u16* pWcom  = (u16*)alloc(16384*2);
  u16* pWper  = (u16*)alloc(16384*2);
  u16* pWrel3 = (u16*)alloc(16384*2);
  u16* pWv    = (u16*)alloc(16384*2);
  u16* pAr    = (u16*)alloc((size_t)RREL*16384*2);
  u16* pWbot  = (u16*)alloc((size_t)6*16384*2);
  (void)ws_size; (void)in_sizes; (void)n_in; (void)out_size;

  // ebC/ebD live in d_out (dead until final GEMM)
  u16* ebC = (u16*)d_out;
  u16* ebD = ebC + (size_t)NT*128;

  // sort temporaries alias dead regions
  int*   bsrc  = (int*)ebA;
  int*   bkey  = bsrc + ETOT;
  float* bew   = (float*)(bkey + ETOT);
  int*   gcntT = (int*)acc16;
  int*   poffT = gcntT + P1B*NBUK;
  int*   btot  = poffT + P1B*NBUK;
  int*   bbase = btot + NBUK;

  hipMemsetAsync(bflag, 0, 4, stream);

  k_bin<<<P1B,256,0,stream>>>(eidx, eweight, bsrc, bkey, bew, gcntT, poffT);
  k_bsum<<<NBUK,256,0,stream>>>(gcntT, btot);
  k_bscan<<<1,256,0,stream>>>(btot, bbase);
  k_place<<<NBUK,256,0,stream>>>(bsrc,bkey,bew,gcntT,poffT,bbase,
                                 starts_g,ends_g,ssrc,sew);

  k_prep<<<(RREL*16384+255)/256,256,0,stream>>>(Wq,bq,Wk,bk,Ar,ur,wr,cr,bflag);

  const int attr[6] = {0,1,2,4,5,6};
  PackJobs pj{};
  int nj=0;
  auto addjob=[&](const float* s,u16* d,int ks){ pj.j[nj].src=s; pj.j[nj].dst=d; pj.j[nj].ksteps=ks; nj++; };
  addjob(W_com,pWcom,4); addjob(W_per,pWper,4);
  addjob(Wrel3,pWrel3,4); addjob(Wv,pWv,4);
  for(int r=0;r<RREL;r++) addjob(Ar + (size_t)r*16384, pAr + (size_t)r*16384, 4);
  for(int i=0;i<6;i++) addjob(Wpair + (size_t)attr[i]*32768 + 16384, pWbot + (size_t)i*16384, 4);
  dim3 pg(16, nj);
  k_pack<<<pg,256,0,stream>>>(pj);

  GArgs g{};
  g = GArgs{}; g.A=company; g.B=pWcom; g.M=NCY; g.rowoff=0; g.outH=emb16;
  k_gemm<0,1><<<(NCY+63)/64,256,0,stream>>>(g);
  g = GArgs{}; g.A=person; g.B=pWper; g.M=NPR; g.rowoff=NCY; g.outH=emb16;
  k_gemm<0,1><<<(NPR+63)/64,256,0,stream>>>(g);

  // bootstrap: ebA = exp(emb @ Wbot[rel0])
  g = GArgs{}; g.A=emb16; g.B=pWbot; g.M=NT; g.outH=ebA;
  k_gemm<4,0><<<(NT+63)/64,256,0,stream>>>(g);

  int NBLK = (NT+63)/64;
  auto mkP = [&](int r1,int r2,const u16* eb1,const u16* eb2,
                 int sa,int sb,u16* w1,u16* w2)->PArgs{
    PArgs P{};
    P.emb16=emb16; P.ssrc=ssrc; P.starts_g=starts_g; P.ends_g=ends_g; P.sew=sew;
    P.ebR1=eb1; P.ebR2=eb2;
    P.pA1=pAr+(size_t)r1*16384; P.pA2=pAr+(size_t)r2*16384;
    P.pWr3=pWrel3;
    P.pB2a=(sa>=0)? pWbot+(size_t)sa*16384 : nullptr;
    P.pB2b=(sb>=0)? pWbot+(size_t)sb*16384 : nullptr;
    P.ebW1=w1; P.ebW2=w2;
    P.acc16=acc16; P.den=den;
    P.u1=ur+(size_t)r1*128; P.w1=wr+(size_t)r1*128; P.c1=cr+r1; P.p1=pri+r1;
    P.u2=ur+(size_t)r2*128; P.w2=wr+(size_t)r2*128; P.c2=cr+r2; P.p2=pri+r2;
    P.bflag=bflag; P.r1=r1; P.r2=r2;
    return P;
  };

  // pair (3,0): dual-gather t3 + rs0(ebA); STORES acc/den; emits ebot(rel1)->ebC, ebot(rel2)->ebD
  k_fp0<<<NBLK,256,0,stream>>>(mkP(3,0, nullptr,ebA, 1,2, ebC,ebD));
  // pair (1,2): dual-gather rs1(ebC), rs2(ebD); emits ebot(rel4)->ebA, ebot(rel5)->ebB
  k_fp<2,2><<<NBLK,256,0,stream>>>(mkP(1,2, ebC,ebD, 3,4, ebA,ebB));
  // pair (4,5): dual-gather rs4(ebA), rs5(ebB); emits ebot(rel6)->ebC
  k_fp<2,1><<<NBLK,256,0,stream>>>(mkP(4,5, ebA,ebB, 5,-1, ebC,nullptr));
  // single (6): gathers rs6(ebC); no emit
  k_fp<1,0><<<NBLK,256,0,stream>>>(mkP(6,6, ebC,nullptr, -1,-1, nullptr,nullptr));

  // final: out = (acc16/den)@Wv + bv + sigmoid(skip)*gelu(emb)
  g = GArgs{}; g.A=acc16; g.B=pWv; g.M=NT;
  g.acc=out; g.den=den; g.emb16=emb16; g.bv=bvv; g.skip=skip;
  k_gemm<3,3><<<(NT+63)/64,256,0,stream>>>(g);
}

// Round 17
// 858.305 us; speedup vs baseline: 1.0763x; 1.0763x over previous
//
#include <hip/hip_runtime.h>
#include <stdint.h>

#define NCY 100000
#define NPR 50000
#define NT  150000
#define RREL 7
#define ETOT 2100000
#define EREL 300000
#define NSEG (RREL*NT)
#define NEG 0.2f

// two-pass sort geometry
#define NBUK 256
#define BWID 587
#define P1B  1024
#define CH1  2051
#define EPT  9
#define LSEG (RREL*BWID)
#define SPT  17

#define LSTR 128      // LDS row stride (u16); XOR granule swizzle

typedef __attribute__((ext_vector_type(8))) short short8;
typedef __attribute__((ext_vector_type(4))) float f32x4;
typedef unsigned short u16;

__device__ __forceinline__ float bf2f(u16 h){
  union{unsigned int u; float f;} v; v.u = ((unsigned int)h)<<16; return v.f;
}
__device__ __forceinline__ u16 f2bf(float f){
  union{unsigned int u; float f;} v; v.f=f;
  unsigned int u=v.u;
  return (u16)((u + 0x7fffu + ((u>>16)&1u))>>16);
}
__device__ __forceinline__ float lrelu(float x){ return x>0.f? x : NEG*x; }
__device__ __forceinline__ int lidx(int row, int col){
  return row*LSTR + ((((col>>4)^(row&7)))<<4) + (col&15);
}

#define MFMA(a,b,c) __builtin_amdgcn_mfma_f32_16x16x32_bf16(a,b,c,0,0,0)

// ============ two-pass counting sort (round-8 proven) ============
__global__ __launch_bounds__(256) void k_bin(const int* __restrict__ eidx,
    const float* __restrict__ ew,
    int* __restrict__ bsrc, int* __restrict__ bkey, float* __restrict__ bew,
    int* __restrict__ gcntT, int* __restrict__ poffT){
  __shared__ int cnt[NBUK];
  __shared__ int pb[NBUK];
  int blk = blockIdx.x, tid = threadIdx.x;
  int base = blk*CH1;
  int n = min(CH1, ETOT-base);
  cnt[tid]=0;
  __syncthreads();
  int esrc[EPT], ekey[EPT], erank[EPT], ebuk[EPT]; float eew[EPT];
  #pragma unroll
  for(int k=0;k<EPT;k++){
    int i = k*256 + tid;
    erank[k]=-1; esrc[k]=0; ekey[k]=0; ebuk[k]=0; eew[k]=0.f;
    if(i<n){
      int e = base+i;
      int2 sd = *(const int2*)(eidx+2*e);
      int r = e/EREL;
      int b = sd.y / BWID;
      esrc[k]=sd.x; ekey[k]=r*NT+sd.y; ebuk[k]=b;
      if(r==3) eew[k]=ew[e];                 // only rel 3 needs edge weights
      erank[k]=atomicAdd(&cnt[b],1);
    }
  }
  __syncthreads();
  int v = cnt[tid];
  pb[tid]=v; __syncthreads();
  for(int off=1; off<256; off<<=1){
    int a=(tid>=off)?pb[tid-off]:0; __syncthreads();
    pb[tid]+=a; __syncthreads();
  }
  int excl = pb[tid]-v;
  gcntT[blk*NBUK+tid]=v;
  poffT[blk*NBUK+tid]=excl;
  pb[tid]=excl; __syncthreads();
  #pragma unroll
  for(int k=0;k<EPT;k++){
    if(erank[k]>=0){
      int pos = base + pb[ebuk[k]] + erank[k];
      bsrc[pos]=esrc[k]; bkey[pos]=ekey[k];
      if(ekey[k]>=3*NT && ekey[k]<4*NT) bew[pos]=eew[k];
    }
  }
}

__global__ __launch_bounds__(256) void k_bsum(const int* __restrict__ gcntT,
                                              int* __restrict__ btot){
  __shared__ int lds[256];
  int b = blockIdx.x, t = threadIdx.x;
  int s=0;
  for(int blk=t; blk<P1B; blk+=256) s += gcntT[blk*NBUK+b];
  lds[t]=s; __syncthreads();
  for(int off=128; off>0; off>>=1){ if(t<off) lds[t]+=lds[t+off]; __syncthreads(); }
  if(t==0) btot[b]=lds[0];
}

__global__ __launch_bounds__(256) void k_bscan(const int* __restrict__ btot,
                                               int* __restrict__ bbase){
  __shared__ int lds[256];
  int t=threadIdx.x;
  int v=btot[t]; lds[t]=v; __syncthreads();
  for(int off=1; off<256; off<<=1){
    int a=(t>=off)?lds[t-off]:0; __syncthreads();
    lds[t]+=a; __syncthreads();
  }
  bbase[t]=lds[t]-v;
}

__global__ __launch_bounds__(256) void k_place(
    const int* __restrict__ bsrc, const int* __restrict__ bkey, const float* __restrict__ bew,
    const int* __restrict__ gcntT, const int* __restrict__ poffT, const int* __restrict__ bbase,
    int* __restrict__ starts_g, int* __restrict__ ends_g,
    int* __restrict__ ssrc, float* __restrict__ sew){
  __shared__ int scnt[LSEG];
  __shared__ int lrun[LSEG];
  __shared__ int gofs[P1B];
  __shared__ int gl[P1B];
  __shared__ int scan[256];
  int b = blockIdx.x, t = threadIdx.x;
  int lo = b*BWID;
  int gbase = bbase[b];
  for(int i=t;i<LSEG;i+=256) scnt[i]=0;
  for(int blk=t; blk<P1B; blk+=256){
    gl[blk]   = gcntT[blk*NBUK+b];
    gofs[blk] = poffT[blk*NBUK+b];
  }
  __syncthreads();
  for(int blk=t; blk<P1B; blk+=256){
    int o = blk*CH1 + gofs[blk], g = gl[blk];
    for(int i=0;i<g;i++){
      int key = bkey[o+i];
      int r = key/NT; int dst = key - r*NT;
      atomicAdd(&scnt[r*BWID + (dst-lo)], 1);
    }
  }
  __syncthreads();
  int ts=0;
  #pragma unroll
  for(int k=0;k<SPT;k++){ int idx=t*SPT+k; ts += (idx<LSEG)? scnt[idx]:0; }
  scan[t]=ts; __syncthreads();
  for(int off=1; off<256; off<<=1){
    int a=(t>=off)?scan[t-off]:0; __syncthreads();
    scan[t]+=a; __syncthreads();
  }
  int run = scan[t]-ts;
  #pragma unroll
  for(int k=0;k<SPT;k++){
    int idx=t*SPT+k;
    if(idx<LSEG){ lrun[idx]=run; run += scnt[idx]; }
  }
  __syncthreads();
  for(int idx=t; idx<LSEG; idx+=256){
    int r = idx/BWID; int ld = idx - r*BWID; int dst = lo+ld;
    if(dst<NT){
      int sgp = gbase + lrun[idx];
      starts_g[r*NT+dst] = sgp;
      ends_g[r*NT+dst]   = sgp + scnt[idx];
    }
  }
  __syncthreads();
  for(int idx=t; idx<LSEG; idx+=256) lrun[idx] += gbase;
  __syncthreads();
  for(int blk=t; blk<P1B; blk+=256){
    int o = blk*CH1 + gofs[blk], g = gl[blk];
    for(int i=0;i<g;i++){
      int key = bkey[o+i];
      int r = key/NT; int dst = key - r*NT;
      int pos = atomicAdd(&lrun[r*BWID+(dst-lo)], 1);
      ssrc[pos] = bsrc[o+i];
      if(r==3) sew[pos] = bew[o+i];
    }
  }
}

// ---------------- A_r = Wq_r Wk_r^T etc ----------------
__global__ __launch_bounds__(256) void k_prep(const float* __restrict__ Wq, const float* __restrict__ bq,
    const float* __restrict__ Wk, const float* __restrict__ bk,
    float* __restrict__ Ar, float* __restrict__ ur, float* __restrict__ wr,
    float* __restrict__ cr, int* __restrict__ bflag){
  int t = blockIdx.x*256 + threadIdx.x;
  if(t >= RREL*128*128) return;
  int r = t/(128*128); int ij = t - r*128*128; int i = ij>>7, j = ij&127;
  const float* wq = Wq + r*16384; const float* wk = Wk + r*16384;
  float s=0.f;
  for(int k=0;k<128;k++) s += wq[i*128+k]*wk[j*128+k];
  Ar[t] = s;
  if(i==0){
    float su=0.f, sw=0.f;
    for(int k=0;k<128;k++){ su += wq[j*128+k]*bk[r*128+k];
                            sw += wk[j*128+k]*bq[r*128+k]; }
    ur[r*128+j]=su; wr[r*128+j]=sw;
    if(j==0){
      float sc=0.f; int nz=0;
      for(int k=0;k<128;k++){ float a=bq[r*128+k], b2=bk[r*128+k];
        sc += a*b2; nz |= (a!=0.f)||(b2!=0.f); }
      cr[r]=sc; if(nz) atomicOr(bflag,1);
    }
  }
}

// ---------------- pack fp32 [K,128] into bf16 MFMA B-fragment layout ----------------
struct PackJob{ const float* src; u16* dst; int ksteps; };
struct PackJobs{ PackJob j[20]; };
__global__ __launch_bounds__(256) void k_pack(PackJobs jobs){
  PackJob J = jobs.j[blockIdx.y];
  int t = blockIdx.x*256 + threadIdx.x;
  int lane = t&63, ks=(t>>6)&7, nt=t>>9;
  if(ks >= J.ksteps) return;
  int col = nt*16 + (lane&15);
  int krow = ks*32 + (lane>>4)*8;
  u16* d = J.dst + ((nt*J.ksteps + ks)*64 + lane)*8;
  for(int j=0;j<8;j++) d[j] = f2bf(J.src[(krow+j)*128 + col]);
}

// ---------------- generic GEMM: EPI 0 emb->bf16, EPI 4 exp->bf16, EPI 3 final ----------------
struct GArgs {
  const void* A; const u16* B; int M; int rowoff;
  u16* outH; float* acc; float* den;
  const u16* emb16;
  const float* bv; const float* skip;
};

template<int EPI, int ASRC>
__global__ __launch_bounds__(256) void k_gemm(GArgs G)
{
  int wave = threadIdx.x>>6, lane = threadIdx.x&63;
  int M = G.M;
  int base = blockIdx.x*64 + wave*16;
  if(base >= M) return;
  int arow = base + (lane&15); if(arow >= M) arow = M-1;
  int kof = (lane>>4)*8;
  short8 a[4];
  if(ASRC==0){
    const u16* A = (const u16*)G.A;
    #pragma unroll
    for(int ks=0;ks<4;ks++) a[ks] = *(const short8*)(A + (size_t)arow*128 + ks*32 + kof);
  } else if(ASRC==3){
    const u16* A = (const u16*)G.A;
    float sc = 1.f/G.den[arow];
    #pragma unroll
    for(int ks=0;ks<4;ks++){
      short8 v = *(const short8*)(A + (size_t)arow*128 + ks*32 + kof);
      short8 s;
      #pragma unroll
      for(int j2=0;j2<8;j2++) s[j2]=f2bf(bf2f((u16)v[j2])*sc);
      a[ks]=s;
    }
  } else {
    const float* A = (const float*)G.A;
    #pragma unroll
    for(int ks=0;ks<4;ks++){
      const float* ap = A + (size_t)arow*128 + ks*32 + kof;
      f32x4 lo = *(const f32x4*)ap;
      f32x4 hi = *(const f32x4*)(ap+4);
      short8 s;
      #pragma unroll
      for(int j2=0;j2<4;j2++){ s[j2]=f2bf(lo[j2]); s[4+j2]=f2bf(hi[j2]); }
      a[ks]=s;
    }
  }
  f32x4 acc[8];
  #pragma unroll
  for(int nt=0;nt<8;nt++){
    f32x4 c = {0.f,0.f,0.f,0.f};
    #pragma unroll
    for(int ks=0;ks<4;ks++){
      short8 b = *(const short8*)(G.B + ((nt*4+ks)*64 + lane)*8);
      c = MFMA(a[ks], b, c);
    }
    acc[nt]=c;
  }
  int rbase = base + (lane>>4)*4;
  int cl = lane&15;
  if(EPI==0){
    #pragma unroll
    for(int nt=0;nt<8;nt++)
      for(int j=0;j<4;j++){
        int row=rbase+j;
        if(row<M){
          int col=nt*16+cl;
          G.outH[(size_t)(G.rowoff+row)*128+col] = f2bf(acc[nt][j]);
        }
      }
  } else if(EPI==4){
    #pragma unroll
    for(int nt=0;nt<8;nt++)
      for(int j=0;j<4;j++){
        int row=rbase+j;
        if(row<M){
          int col=nt*16+cl;
          G.outH[(size_t)row*128+col]=f2bf(__expf(acc[nt][j]));
        }
      }
  } else { // EPI==3
    float sg = 1.f/(1.f+__expf(-G.skip[0]));
    #pragma unroll
    for(int nt=0;nt<8;nt++)
      for(int j=0;j<4;j++){
        int row=rbase+j;
        if(row<M){
          int col=nt*16+cl;
          float x = bf2f(G.emb16[(size_t)row*128+col]);
          float g = 0.5f*x*(1.f+erff(x*0.70710678118f));
          G.acc[(size_t)row*128+col] = acc[nt][j] + G.bv[col] + sg*g;
        }
      }
  }
}

// ================= fused pair kernels =================
struct PArgs {
  const u16* emb16; const int* ssrc; const int* starts_g; const int* ends_g;
  const float* sew;
  const u16* ebR1; const u16* ebR2;
  const u16* pA1; const u16* pA2;
  const u16* pWr3;
  const u16* pB2a; const u16* pB2b; u16* ebW1; u16* ebW2;
  u16* acc16; float* den;
  const float* u1; const float* w1; const float* c1; const float* p1;
  const float* u2; const float* w2; const float* c2; const float* p2;
  const int* bflag;
  int r1, r2;
};

// gather one att relation's rs rows into swizzled LDS tile [64][LSTR] (2-pass, 8 thr/node, 2-edge unroll)
__device__ __forceinline__ void gatherAtt(u16* buf, const u16* __restrict__ ebt,
    const u16* __restrict__ emb16, const int* __restrict__ ssrc,
    const int* __restrict__ sg, const int* __restrict__ eg,
    int rel, int base64, int tid){
  #pragma unroll
  for(int p2=0;p2<2;p2++){
    int ln = (tid>>3) + p2*32;
    int gn = base64 + ln;
    int cb = (tid&7)*16;
    float num[16]={0,0,0,0,0,0,0,0,0,0,0,0,0,0,0,0};
    float den[16]={0,0,0,0,0,0,0,0,0,0,0,0,0,0,0,0};
    if(gn<NT){
      int s=sg[rel*NT+gn], e=eg[rel*NT+gn];
      int pos=s;
      for(; pos+1<e; pos+=2){
        int s0=ssrc[pos], s1=ssrc[pos+1];
        const u16* eb0=ebt+(size_t)s0*128+cb;   const u16* xm0=emb16+(size_t)s0*128+cb;
        const u16* eb1=ebt+(size_t)s1*128+cb;   const u16* xm1=emb16+(size_t)s1*128+cb;
        short8 ea0=*(const short8*)eb0, ea1=*(const short8*)(eb0+8);
        short8 xa0=*(const short8*)xm0, xa1=*(const short8*)(xm0+8);
        short8 eb0v=*(const short8*)eb1, eb1v=*(const short8*)(eb1+8);
        short8 xb0=*(const short8*)xm1, xb1=*(const short8*)(xm1+8);
        #pragma unroll
        for(int j=0;j<8;j++){
          float e00=bf2f((u16)ea0[j]), e01=bf2f((u16)ea1[j]);
          float e10=bf2f((u16)eb0v[j]), e11=bf2f((u16)eb1v[j]);
          num[j]   += bf2f((u16)xa0[j])*e00 + bf2f((u16)xb0[j])*e10;
          den[j]   += e00 + e10;
          num[8+j] += bf2f((u16)xa1[j])*e01 + bf2f((u16)xb1[j])*e11;
          den[8+j] += e01 + e11;
        }
      }
      if(pos<e){
        int s0=ssrc[pos];
        const u16* eb0=ebt+(size_t)s0*128+cb;  const u16* xm0=emb16+(size_t)s0*128+cb;
        short8 ea0=*(const short8*)eb0, ea1=*(const short8*)(eb0+8);
        short8 xa0=*(const short8*)xm0, xa1=*(const short8*)(xm0+8);
        #pragma unroll
        for(int j=0;j<8;j++){
          float e00=bf2f((u16)ea0[j]), e01=bf2f((u16)ea1[j]);
          num[j]   += bf2f((u16)xa0[j])*e00; den[j]   += e00;
          num[8+j] += bf2f((u16)xa1[j])*e01; den[8+j] += e01;
        }
      }
    }
    short8 v0, v1;
    #pragma unroll
    for(int j=0;j<8;j++){
      v0[j] = (short)f2bf(lrelu(num[j]/(den[j]+1e-16f)));
      v1[j] = (short)f2bf(lrelu(num[8+j]/(den[8+j]+1e-16f)));
    }
    int g1 = (tid&7) ^ (ln&7);
    u16* wp = buf + ln*LSTR + g1*16;
    *(short8*)wp = v0;
    *(short8*)(wp+8) = v1;
  }
}

// gather rel-3 weighted mean t into swizzled LDS (no lrelu, 2-edge unroll)
__device__ __forceinline__ void gatherR3(u16* buf, const float* __restrict__ sew,
    const u16* __restrict__ emb16, const int* __restrict__ ssrc,
    const int* __restrict__ sg, const int* __restrict__ eg,
    int base64, int tid){
  #pragma unroll
  for(int p2=0;p2<2;p2++){
    int ln = (tid>>3) + p2*32;
    int gn = base64 + ln;
    int cb = (tid&7)*16;
    float num[16]={0,0,0,0,0,0,0,0,0,0,0,0,0,0,0,0};
    float dn=0.f;
    if(gn<NT){
      int s=sg[3*NT+gn], e=eg[3*NT+gn];
      int pos=s;
      for(; pos+1<e; pos+=2){
        int s0=ssrc[pos], s1=ssrc[pos+1];
        float w0=__expf(sew[pos]), w1=__expf(sew[pos+1]);
        dn += w0 + w1;
        const u16* xm0=emb16+(size_t)s0*128+cb;
        const u16* xm1=emb16+(size_t)s1*128+cb;
        short8 xa0=*(const short8*)xm0, xa1=*(const short8*)(xm0+8);
        short8 xb0=*(const short8*)xm1, xb1=*(const short8*)(xm1+8);
        #pragma unroll
        for(int j=0;j<8;j++){
          num[j]   += w0*bf2f((u16)xa0[j]) + w1*bf2f((u16)xb0[j]);
          num[8+j] += w0*bf2f((u16)xa1[j]) + w1*bf2f((u16)xb1[j]);
        }
      }
      if(pos<e){
        int s0=ssrc[pos];
        float w0=__expf(sew[pos]);
        dn += w0;
        const u16* xm0=emb16+(size_t)s0*128+cb;
        short8 xa0=*(const short8*)xm0, xa1=*(const short8*)(xm0+8);
        #pragma unroll
        for(int j=0;j<8;j++){
          num[j]   += w0*bf2f((u16)xa0[j]);
          num[8+j] += w0*bf2f((u16)xa1[j]);
        }
      }
    }
    float inv=1.f/(dn+1e-16f);
    short8 v0, v1;
    #pragma unroll
    for(int j=0;j<8;j++){
      v0[j] = (short)f2bf(num[j]*inv);
      v1[j] = (short)f2bf(num[8+j]*inv);
    }
    int g1 = (tid&7) ^ (ln&7);
    u16* wp = buf + ln*LSTR + g1*16;
    *(short8*)wp = v0;
    *(short8*)(wp+8) = v1;
  }
}

// generic fused pair kernel. NR = #relations, NEB = #ebot emits. (RMW acc)
template<int NR, int NEB>
__global__ __launch_bounds__(256) void k_fp(PArgs P)
{
  __shared__ u16 ldsA[(NR==2 ? 2 : 1)*64*LSTR];
  u16* lds1 = ldsA;
  u16* lds2 = ldsA + (NR==2 ? 64*LSTR : 0);
  int tid = threadIdx.x;
  int base64 = blockIdx.x*64;
  gatherAtt(lds1, P.ebR1, P.emb16, P.ssrc, P.starts_g, P.ends_g, P.r1, base64, tid);
  if(NR==2) gatherAtt(lds2, P.ebR2, P.emb16, P.ssrc, P.starts_g, P.ends_g, P.r2, base64, tid);
  __syncthreads();
  int wave=tid>>6, lane=tid&63;
  int base = base64 + wave*16;
  if(base >= NT) return;
  int arow = base + (lane&15); if(arow >= NT) arow = NT-1;
  int kof = (lane>>4)*8;
  short8 a[4];
  #pragma unroll
  for(int ks=0;ks<4;ks++) a[ks] = *(const short8*)(P.emb16 + (size_t)arow*128 + ks*32 + kof);
  int rbase = base + (lane>>4)*4;
  int lrb   = wave*16 + (lane>>4)*4;
  int cl = lane&15;
  int bias = *P.bflag;
  float e1v[4], e2v[4];
  // --- score r1 ---
  {
    f32x4 accS[8];
    #pragma unroll
    for(int nt=0;nt<8;nt++){
      f32x4 c = {0.f,0.f,0.f,0.f};
      #pragma unroll
      for(int ks=0;ks<4;ks++){
        short8 b = *(const short8*)(P.pA1 + ((nt*4+ks)*64 + lane)*8);
        c = MFMA(a[ks], b, c);
      }
      accS[nt]=c;
    }
    float prival = P.p1[0]*0.08838834764831845f;
    #pragma unroll
    for(int j=0;j<4;j++){
      int row=rbase+j; bool ok=row<NT;
      float p=0.f;
      if(ok){
        #pragma unroll
        for(int nt=0;nt<8;nt++){
          int col=nt*16+cl;
          float rv = bf2f(lds1[lidx(lrb+j,col)]);
          p += accS[nt][j]*rv;
          if(bias) p += bf2f(P.emb16[(size_t)row*128+col])*P.u1[col] + rv*P.w1[col];
        }
      }
      p += __shfl_xor(p,1,16); p += __shfl_xor(p,2,16);
      p += __shfl_xor(p,4,16); p += __shfl_xor(p,8,16);
      e1v[j] = __expf((p + P.c1[0])*prival);
    }
  }
  // --- score r2 ---
  if(NR==2){
    f32x4 accS[8];
    #pragma unroll
    for(int nt=0;nt<8;nt++){
      f32x4 c = {0.f,0.f,0.f,0.f};
      #pragma unroll
      for(int ks=0;ks<4;ks++){
        short8 b = *(const short8*)(P.pA2 + ((nt*4+ks)*64 + lane)*8);
        c = MFMA(a[ks], b, c);
      }
      accS[nt]=c;
    }
    float prival = P.p2[0]*0.08838834764831845f;
    #pragma unroll
    for(int j=0;j<4;j++){
      int row=rbase+j; bool ok=row<NT;
      float p=0.f;
      if(ok){
        #pragma unroll
        for(int nt=0;nt<8;nt++){
          int col=nt*16+cl;
          float rv = bf2f(lds2[lidx(lrb+j,col)]);
          p += accS[nt][j]*rv;
          if(bias) p += bf2f(P.emb16[(size_t)row*128+col])*P.u2[col] + rv*P.w2[col];
        }
      }
      p += __shfl_xor(p,1,16); p += __shfl_xor(p,2,16);
      p += __shfl_xor(p,4,16); p += __shfl_xor(p,8,16);
      e2v[j] = __expf((p + P.c2[0])*prival);
    }
  }
  // --- single RMW accumulate ---
  #pragma unroll
  for(int j=0;j<4;j++){
    int row=rbase+j;
    if(row<NT){
      float ee1=e1v[j];
      float ee2=(NR==2)? e2v[j] : 0.f;
      #pragma unroll
      for(int nt=0;nt<8;nt++){
        int col=nt*16+cl;
        size_t o=(size_t)row*128+col;
        float add = ee1*bf2f(lds1[lidx(lrb+j,col)]);
        if(NR==2) add += ee2*bf2f(lds2[lidx(lrb+j,col)]);
        P.acc16[o] = f2bf(bf2f(P.acc16[o]) + add);
      }
      if(cl==0) P.den[row] += ee1 + ee2;
    }
  }
  // --- emit next ebot tables ---
  if(NEB>=1){
    #pragma unroll
    for(int nt=0;nt<8;nt++){
      f32x4 c = {0.f,0.f,0.f,0.f};
      #pragma unroll
      for(int ks=0;ks<4;ks++){
        short8 b = *(const short8*)(P.pB2a + ((nt*4+ks)*64 + lane)*8);
        c = MFMA(a[ks], b, c);
      }
      #pragma unroll
      for(int j=0;j<4;j++){
        int row=rbase+j;
        if(row<NT) P.ebW1[(size_t)row*128 + nt*16+cl] = f2bf(__expf(c[j]));
      }
    }
  }
  if(NEB>=2){
    #pragma unroll
    for(int nt=0;nt<8;nt++){
      f32x4 c = {0.f,0.f,0.f,0.f};
      #pragma unroll
      for(int ks=0;ks<4;ks++){
        short8 b = *(const short8*)(P.pB2b + ((nt*4+ks)*64 + lane)*8);
        c = MFMA(a[ks], b, c);
      }
      #pragma unroll
      for(int j=0;j<4;j++){
        int row=rbase+j;
        if(row<NT) P.ebW2[(size_t)row*128 + nt*16+cl] = f2bf(__expf(c[j]));
      }
    }
  }
}

// fused pair (rel3, rel0): FIRST accumulator -> STORE acc/den (no RMW, no memset needed)
__global__ __launch_bounds__(256) void k_fp0(PArgs P)
{
  __shared__ u16 lds1[64*LSTR];   // t3 (A-layout consumption)
  __shared__ u16 lds2[64*LSTR];   // rs0
  int tid = threadIdx.x;
  int base64 = blockIdx.x*64;
  gatherR3(lds1, P.sew, P.emb16, P.ssrc, P.starts_g, P.ends_g, base64, tid);
  gatherAtt(lds2, P.ebR2, P.emb16, P.ssrc, P.starts_g, P.ends_g, P.r2, base64, tid);
  __syncthreads();
  int wave=tid>>6, lane=tid&63;
  int base = base64 + wave*16;
  if(base >= NT) return;
  int arow = base + (lane&15); if(arow >= NT) arow = NT-1;
  int hi = lane>>4;
  int kof = hi*8;
  int lar = wave*16 + (lane&15);
  short8 a[4];
  #pragma unroll
  for(int ks=0;ks<4;ks++) a[ks] = *(const short8*)(P.emb16 + (size_t)arow*128 + ks*32 + kof);
  // rs3 = lrelu(t3 @ Wrel3) from swizzled lds1
  f32x4 rs3[8];
  {
    short8 ta[4];
    #pragma unroll
    for(int ks=0;ks<4;ks++){
      int g = ((ks<<1)+(hi>>1)) ^ (lar&7);
      ta[ks] = *(const short8*)(lds1 + lar*LSTR + g*16 + ((hi&1)<<3));
    }
    #pragma unroll
    for(int nt=0;nt<8;nt++){
      f32x4 c = {0.f,0.f,0.f,0.f};
      #pragma unroll
      for(int ks=0;ks<4;ks++){
        short8 b = *(const short8*)(P.pWr3 + ((nt*4+ks)*64 + lane)*8);
        c = MFMA(ta[ks], b, c);
      }
      #pragma unroll
      for(int j=0;j<4;j++) c[j] = lrelu(c[j]);
      rs3[nt]=c;
    }
  }
  int rbase = base + (lane>>4)*4;
  int lrb   = wave*16 + (lane>>4)*4;
  int cl = lane&15;
  int bias = *P.bflag;
  float e1v[4], e2v[4];
  // --- score rel3 (rs from registers) ---
  {
    f32x4 accS[8];
    #pragma unroll
    for(int nt=0;nt<8;nt++){
      f32x4 c = {0.f,0.f,0.f,0.f};
      #pragma unroll
      for(int ks=0;ks<4;ks++){
        short8 b = *(const short8*)(P.pA1 + ((nt*4+ks)*64 + lane)*8);
        c = MFMA(a[ks], b, c);
      }
      accS[nt]=c;
    }
    float prival = P.p1[0]*0.08838834764831845f;
    #pragma unroll
    for(int j=0;j<4;j++){
      int row=rbase+j; bool ok=row<NT;
      float p=0.f;
      if(ok){
        #pragma unroll
        for(int nt=0;nt<8;nt++){
          int col=nt*16+cl;
          float rv = rs3[nt][j];
          p += accS[nt][j]*rv;
          if(bias) p += bf2f(P.emb16[(size_t)row*128+col])*P.u1[col] + rv*P.w1[col];
        }
      }
      p += __shfl_xor(p,1,16); p += __shfl_xor(p,2,16);
      p += __shfl_xor(p,4,16); p += __shfl_xor(p,8,16);
      e1v[j] = __expf((p + P.c1[0])*prival);
    }
  }
  // --- score rel0 (rs from LDS) ---
  {
    f32x4 accS[8];
    #pragma unroll
    for(int nt=0;nt<8;nt++){
      f32x4 c = {0.f,0.f,0.f,0.f};
      #pragma unroll
      for(int ks=0;ks<4;ks++){
        short8 b = *(const short8*)(P.pA2 + ((nt*4+ks)*64 + lane)*8);
        c = MFMA(a[ks], b, c);
      }
      accS[nt]=c;
    }
    float prival = P.p2[0]*0.08838834764831845f;
    #pragma unroll
    for(int j=0;j<4;j++){
      int row=rbase+j; bool ok=row<NT;
      float p=0.f;
      if(ok){
        #pragma unroll
        for(int nt=0;nt<8;nt++){
          int col=nt*16+cl;
          float rv = bf2f(lds2[lidx(lrb+j,col)]);
          p += accS[nt][j]*rv;
          if(bias) p += bf2f(P.emb16[(size_t)row*128+col])*P.u2[col] + rv*P.w2[col];
        }
      }
      p += __shfl_xor(p,1,16); p += __shfl_xor(p,2,16);
      p += __shfl_xor(p,4,16); p += __shfl_xor(p,8,16);
      e2v[j] = __expf((p + P.c2[0])*prival);
    }
  }
  // --- STORE (first accumulator; f2bf(x) == f2bf(0+x), bit-identical to memset+RMW) ---
  #pragma unroll
  for(int j=0;j<4;j++){
    int row=rbase+j;
    if(row<NT){
      float ee1=e1v[j], ee2=e2v[j];
      #pragma unroll
      for(int nt=0;nt<8;nt++){
        int col=nt*16+cl;
        size_t o=(size_t)row*128+col;
        float add = ee1*bf2f(f2bf(rs3[nt][j])) + ee2*bf2f(lds2[lidx(lrb+j,col)]);
        P.acc16[o] = f2bf(add);
      }
      if(cl==0) P.den[row] = ee1 + ee2;
    }
  }
  // --- emit ebot for rel1, rel2 ---
  #pragma unroll
  for(int nt=0;nt<8;nt++){
    f32x4 c = {0.f,0.f,0.f,0.f};
    #pragma unroll
    for(int ks=0;ks<4;ks++){
      short8 b = *(const short8*)(P.pB2a + ((nt*4+ks)*64 + lane)*8);
      c = MFMA(a[ks], b, c);
    }
    #pragma unroll
    for(int j=0;j<4;j++){
      int row=rbase+j;
      if(row<NT) P.ebW1[(size_t)row*128 + nt*16+cl] = f2bf(__expf(c[j]));
    }
  }
  #pragma unroll
  for(int nt=0;nt<8;nt++){
    f32x4 c = {0.f,0.f,0.f,0.f};
    #pragma unroll
    for(int ks=0;ks<4;ks++){
      short8 b = *(const short8*)(P.pB2b + ((nt*4+ks)*64 + lane)*8);
      c = MFMA(a[ks], b, c);
    }
    #pragma unroll
    for(int j=0;j<4;j++){
      int row=rbase+j;
      if(row<NT) P.ebW2[(size_t)row*128 + nt*16+cl] = f2bf(__expf(c[j]));
    }
  }
}

extern "C" void kernel_launch(void* const* d_in, const int* in_sizes, int n_in,
                              void* d_out, int out_size, void* d_ws, size_t ws_size,
                              hipStream_t stream){
  const float* company = (const float*)d_in[0];
  const float* person  = (const float*)d_in[1];
  const float* eweight = (const float*)d_in[2];
  const float* W_com   = (const float*)d_in[3];
  const float* W_per   = (const float*)d_in[4];
  const float* Wq      = (const float*)d_in[5];
  const float* bq      = (const float*)d_in[6];
  const float* Wk      = (const float*)d_in[7];
  const float* bk      = (const float*)d_in[8];
  const float* Wv      = (const float*)d_in[9];
  const float* bvv     = (const float*)d_in[10];
  const float* pri     = (const float*)d_in[11];
  const float* Wpair   = (const float*)d_in[12];
  const float* Wrel3   = (const float*)d_in[13];
  const float* skip    = (const float*)d_in[14];
  const int*   eidx    = (const int*)d_in[15];
  float* out = (float*)d_out;

  // workspace (~181 MB, known-good level)
  char* w = (char*)d_ws;
  auto alloc = [&](size_t sz)->void*{ void* p=(void*)w; w += (sz+255)&~(size_t)255; return p; };
  u16*   emb16 = (u16*)alloc((size_t)NT*128*2);
  u16*   ebA   = (u16*)alloc((size_t)NT*128*2);        // aliases sort bsrc/bkey/bew
  u16*   ebB   = (u16*)alloc((size_t)NT*128*2);
  u16*   acc16 = (u16*)alloc((size_t)NT*128*2);        // aliases gcntT/poffT/btot/bbase
  float* den   = (float*)alloc((size_t)NT*4);
  int*   starts_g = (int*)alloc((size_t)NSEG*4);
  int*   ends_g   = (int*)alloc((size_t)NSEG*4);
  int*   ssrc  = (int*)alloc((size_t)ETOT*4);
  float* sew   = (float*)alloc((size_t)ETOT*4);
  float* Ar    = (float*)alloc((size_t)RREL*16384*4);
  float* ur    = (float*)alloc(RREL*128*4);
  float* wr    = (float*)alloc(RREL*128*4);
  float* cr    = (float*)alloc(RREL*4);
  int*   bflag = (int*)alloc(256);
  u16* pWcom  = (u16*)alloc(16384*2);
  u16* pWper  = (u16*)alloc(16384*2);
  u16* pWrel3 = (u16*)alloc(16384*2);
  u16* pWv    = (u16*)alloc(16384*2);
  u16* pAr    = (u16*)alloc((size_t)RREL*16384*2);
  u16* pWbot  = (u16*)alloc((size_t)6*16384*2);
  (void)ws_size; (void)in_sizes; (void)n_in; (void)out_size;

  // ebC/ebD live in d_out (dead until final GEMM)
  u16* ebC = (u16*)d_out;
  u16* ebD = ebC + (size_t)NT*128;

  // sort temporaries alias dead regions
  int*   bsrc  = (int*)ebA;
  int*   bkey  = bsrc + ETOT;
  float* bew   = (float*)(bkey + ETOT);
  int*   gcntT = (int*)acc16;
  int*   poffT = gcntT + P1B*NBUK;
  int*   btot  = poffT + P1B*NBUK;
  int*   bbase = btot + NBUK;

  hipMemsetAsync(bflag, 0, 4, stream);

  k_bin<<<P1B,256,0,stream>>>(eidx, eweight, bsrc, bkey, bew, gcntT, poffT);
  k_bsum<<<NBUK,256,0,stream>>>(gcntT, btot);
  k_bscan<<<1,256,0,stream>>>(btot, bbase);
  k_place<<<NBUK,256,0,stream>>>(bsrc,bkey,bew,gcntT,poffT,bbase,
                                 starts_g,ends_g,ssrc,sew);

  k_prep<<<(RREL*16384+255)/256,256,0,stream>>>(Wq,bq,Wk,bk,Ar,ur,wr,cr,bflag);

  const int attr[6] = {0,1,2,4,5,6};
  PackJobs pj{};
  int nj=0;
  auto addjob=[&](const float* s,u16* d,int ks){ pj.j[nj].src=s; pj.j[nj].dst=d; pj.j[nj].ksteps=ks; nj++; };
  addjob(W_com,pWcom,4); addjob(W_per,pWper,4);
  addjob(Wrel3,pWrel3,4); addjob(Wv,pWv,4);
  for(int r=0;r<RREL;r++) addjob(Ar + (size_t)r*16384, pAr + (size_t)r*16384, 4);
  for(int i=0;i<6;i++) addjob(Wpair + (size_t)attr[i]*32768 + 16384, pWbot + (size_t)i*16384, 4);
  dim3 pg(16, nj);
  k_pack<<<pg,256,0,stream>>>(pj);

  GArgs g{};
  g = GArgs{}; g.A=company; g.B=pWcom; g.M=NCY; g.rowoff=0; g.outH=emb16;
  k_gemm<0,1><<<(NCY+63)/64,256,0,stream>>>(g);
  g = GArgs{}; g.A=person; g.B=pWper; g.M=NPR; g.rowoff=NCY; g.outH=emb16;
  k_gemm<0,1><<<(NPR+63)/64,256,0,stream>>>(g);

  // bootstrap: ebA = exp(emb @ Wbot[rel0])
  g = GArgs{}; g.A=emb16; g.B=pWbot; g.M=NT; g.outH=ebA;
  k_gemm<4,0><<<(NT+63)/64,256,0,stream>>>(g);

  int NBLK = (NT+63)/64;
  auto mkP = [&](int r1,int r2,const u16* eb1,const u16* eb2,
                 int sa,int sb,u16* w1,u16* w2)->PArgs{
    PArgs P{};
    P.emb16=emb16; P.ssrc=ssrc; P.starts_g=starts_g; P.ends_g=ends_g; P.sew=sew;
    P.ebR1=eb1; P.ebR2=eb2;
    P.pA1=pAr+(size_t)r1*16384; P.pA2=pAr+(size_t)r2*16384;
    P.pWr3=pWrel3;
    P.pB2a=(sa>=0)? pWbot+(size_t)sa*16384 : nullptr;
    P.pB2b=(sb>=0)? pWbot+(size_t)sb*16384 : nullptr;
    P.ebW1=w1; P.ebW2=w2;
    P.acc16=acc16; P.den=den;
    P.u1=ur+(size_t)r1*128; P.w1=wr+(size_t)r1*128; P.c1=cr+r1; P.p1=pri+r1;
    P.u2=ur+(size_t)r2*128; P.w2=wr+(size_t)r2*128; P.c2=cr+r2; P.p2=pri+r2;
    P.bflag=bflag; P.r1=r1; P.r2=r2;
    return P;
  };

  // pair (3,0): gathers t3 + rs0(ebA); STORES acc/den; emits ebot(rel1)->ebC, ebot(rel2)->ebD
  k_fp0<<<NBLK,256,0,stream>>>(mkP(3,0, nullptr,ebA, 1,2, ebC,ebD));
  // pair (1,2): gathers rs1(ebC), rs2(ebD); emits ebot(rel4)->ebA, ebot(rel5)->ebB
  k_fp<2,2><<<NBLK,256,0,stream>>>(mkP(1,2, ebC,ebD, 3,4, ebA,ebB));
  // pair (4,5): gathers rs4(ebA), rs5(ebB); emits ebot(rel6)->ebC
  k_fp<2,1><<<NBLK,256,0,stream>>>(mkP(4,5, ebA,ebB, 5,-1, ebC,nullptr));
  // single (6): gathers rs6(ebC); no emit
  k_fp<1,0><<<NBLK,256,0,stream>>>(mkP(6,6, ebC,nullptr, -1,-1, nullptr,nullptr));

  // final: out = (acc16/den)@Wv + bv + sigmoid(skip)*gelu(emb)
  g = GArgs{}; g.A=acc16; g.B=pWv; g.M=NT;
  g.acc=out; g.den=den; g.emb16=emb16; g.bv=bvv; g.skip=skip;
  k_gemm<3,3><<<(NT+63)/64,256,0,stream>>>(g);
}